// Round 6
// baseline (5608.427 us; speedup 1.0000x reference)
//
#include <hip/hip_runtime.h>
#include <hip/hip_bf16.h>

#define BB 64
#define TT 64
#define FF 256
#define CC 64
#define GG 256   // 4*C
#define HP 264   // padded f-rows per batch: 4 zero + 256 + 4 zero
#define GST 132  // gbuf row stride (floats): 128 gate-cols + 4 pad

using frag_ab = __attribute__((ext_vector_type(8))) short;  // 8 bf16
using f32x4   = __attribute__((ext_vector_type(4))) float;

__device__ __forceinline__ float sigmoidf_(float x) {
    return 1.0f / (1.0f + __expf(-x));
}
__device__ __forceinline__ float tanhf_(float x) {
    const float e = __expf(2.0f * x);
    return 1.0f - 2.0f / (e + 1.0f);
}
__device__ __forceinline__ void split2(float v, short* hi, short* lo) {
    __hip_bfloat16 h = __float2bfloat16(v);
    __hip_bfloat16 l = __float2bfloat16(v - __bfloat162float(h));
    *hi = *reinterpret_cast<short*>(&h);
    *lo = *reinterpret_cast<short*>(&l);
}

// ---- prep: Wh -> packed [p][g][cin32] hi/lo; Wx -> [g][32] hi/lo;
//      h0 -> padded (B,HP,C) hi/lo, zeroed halos; zero out-reduction slots
__global__ __launch_bounds__(256) void prep_kernel(
    const float* __restrict__ Wh, const float* __restrict__ Wx,
    const float* __restrict__ h0,
    short* __restrict__ WhPh, short* __restrict__ WhPl,
    short* __restrict__ WxTh, short* __restrict__ WxTl,
    short* __restrict__ hAh, short* __restrict__ hAl,
    short* __restrict__ hBh, short* __restrict__ hBl,
    float* __restrict__ accW, int* __restrict__ cntW)
{
    const int n = blockIdx.x * 256 + threadIdx.x;
    if (n < BB * HP * CC) {
        const int c = n & 63;
        const int r = (n >> 6) % HP;
        const int b = n / (HP * CC);
        if (r < 4 || r >= 260) {
            hAh[n] = 0; hAl[n] = 0; hBh[n] = 0; hBl[n] = 0;
        } else {
            split2(h0[(b * FF + (r - 4)) * CC + c], &hAh[n], &hAl[n]);
        }
    }
    if (n < 9 * GG * CC) {
        const int c32 = n & 31;
        const int g = (n >> 5) & 255;
        const int p = n >> 13;
        const int k = p >> 1;
        const int cin = (p & 1) * 32 + c32;
        split2(Wh[(k * CC + cin) * GG + g], &WhPh[n], &WhPl[n]);
    }
    if (n < GG * 32) {
        const int kz = n & 31;
        const int g = n >> 5;
        split2(kz < 9 ? Wx[kz * GG + g] : 0.0f, &WxTh[n], &WxTl[n]);
    }
    if (n < BB * FF) { accW[n] = 0.0f; cntW[n] = 0; }
}

__global__ __launch_bounds__(256, 2) void convlstm_step(
    const float* __restrict__ z,
    const short* __restrict__ hinh, const short* __restrict__ hinl,  // padded (B,HP,C)
    const float* __restrict__ c_in,
    const short* __restrict__ WhPh, const short* __restrict__ WhPl,
    const short* __restrict__ WxTh, const short* __restrict__ WxTl,
    const float* __restrict__ bias,
    short* __restrict__ houth, short* __restrict__ houtl,            // padded
    float* __restrict__ c_out,
    float* __restrict__ accW, int* __restrict__ cntW,
    float* __restrict__ out, int t)
{
    __shared__ __align__(16) char hbyh[72 * 128];   // h hi tile, swizzled
    __shared__ __align__(16) char hbyl[72 * 128];   // h lo tile
    __shared__ __align__(16) char zbyh[64 * 64];    // z hi tile [64 f][32 kz]
    __shared__ __align__(16) char zbyl[64 * 64];
    __shared__ __align__(16) float gbuf[64 * GST];  // 64 f x (4 gates x 32 ch), 33.8 KB

    const int b = blockIdx.x;
    const int f0 = blockIdx.y * 64;
    const int half = blockIdx.z;     // 0/1 : channel half
    const int tid = threadIdx.x;
    const int lane = tid & 63;
    const int q = tid >> 6;          // 0..3 : gate index this wave owns

    // ---- stage h tile rows f0..f0+71 (padded space; always in-bounds)
    for (int idx = tid; idx < 72 * 8; idx += 256) {
        const int row = idx >> 3, slot = idx & 7;
        const int off = (b * HP + f0 + row) * CC + slot * 8;
        const frag_ab vh = *reinterpret_cast<const frag_ab*>(hinh + off);
        const frag_ab vl = *reinterpret_cast<const frag_ab*>(hinl + off);
        const int a = row * 128 + ((slot ^ (row & 7)) << 4);
        *reinterpret_cast<frag_ab*>(&hbyh[a]) = vh;
        *reinterpret_cast<frag_ab*>(&hbyl[a]) = vl;
    }
    // ---- stage z tile [64 f][kz<9] hi+lo
    {
        const int row = tid >> 2, slot = tid & 3;
        const float* zr = z + ((long)b * TT + t) * FF;
        short vh[8], vl[8];
        #pragma unroll
        for (int j = 0; j < 8; ++j) {
            const int kz = slot * 8 + j;
            const int f = f0 + row - 4 + kz;
            const float val = (kz < 9 && f >= 0 && f < FF) ? zr[f] : 0.0f;
            split2(val, &vh[j], &vl[j]);
        }
        const int a = row * 64 + ((slot ^ (row & 3)) << 4);
        *reinterpret_cast<frag_ab*>(&zbyh[a]) = *reinterpret_cast<frag_ab*>(vh);
        *reinterpret_cast<frag_ab*>(&zbyl[a]) = *reinterpret_cast<frag_ab*>(vl);
    }
    __syncthreads();

    const int rA = lane & 15;
    const int sA = lane >> 4;
    const int gbase = q * 64 + half * 32;   // this wave's 32 g-cols

    f32x4 acc[4][2];
    #pragma unroll
    for (int gtI = 0; gtI < 2; ++gtI) {
        const float bv = bias[gbase + gtI * 16 + rA];
        #pragma unroll
        for (int Mt = 0; Mt < 4; ++Mt) acc[Mt][gtI] = (f32x4){bv, bv, bv, bv};
    }

    const int bln = rA * 32 + sA * 8;
    frag_ab cb[4];
    {
        const int o0 = gbase * 32 + bln;
        cb[0] = *reinterpret_cast<const frag_ab*>(WhPh + o0);
        cb[1] = *reinterpret_cast<const frag_ab*>(WhPh + o0 + 16 * 32);
        cb[2] = *reinterpret_cast<const frag_ab*>(WhPl + o0);
        cb[3] = *reinterpret_cast<const frag_ab*>(WhPl + o0 + 16 * 32);
    }

    // ---- 18 Wh phases, B prefetched one phase ahead
    #pragma unroll
    for (int p = 0; p < 18; ++p) {
        frag_ab nb[4];
        if (p < 17) {
            const int o0 = ((p + 1) * GG + gbase) * 32 + bln;
            nb[0] = *reinterpret_cast<const frag_ab*>(WhPh + o0);
            nb[1] = *reinterpret_cast<const frag_ab*>(WhPh + o0 + 16 * 32);
            nb[2] = *reinterpret_cast<const frag_ab*>(WhPl + o0);
            nb[3] = *reinterpret_cast<const frag_ab*>(WhPl + o0 + 16 * 32);
        } else {
            const int o0 = gbase * 32 + bln;
            nb[0] = *reinterpret_cast<const frag_ab*>(WxTh + o0);
            nb[1] = *reinterpret_cast<const frag_ab*>(WxTh + o0 + 16 * 32);
            nb[2] = *reinterpret_cast<const frag_ab*>(WxTl + o0);
            nb[3] = *reinterpret_cast<const frag_ab*>(WxTl + o0 + 16 * 32);
        }
        const int k = p >> 1, kk = p & 1;
        const int sl = kk * 4 + sA;
        frag_ab ah[4], al[4];
        #pragma unroll
        for (int Mt = 0; Mt < 4; ++Mt) {
            const int r = Mt * 16 + rA + k;
            const int a = r * 128 + ((sl ^ (r & 7)) << 4);
            ah[Mt] = *reinterpret_cast<const frag_ab*>(&hbyh[a]);
            al[Mt] = *reinterpret_cast<const frag_ab*>(&hbyl[a]);
        }
        #pragma unroll
        for (int Mt = 0; Mt < 4; ++Mt) {
            acc[Mt][0] = __builtin_amdgcn_mfma_f32_16x16x32_bf16(ah[Mt], cb[0], acc[Mt][0], 0, 0, 0);
            acc[Mt][1] = __builtin_amdgcn_mfma_f32_16x16x32_bf16(ah[Mt], cb[1], acc[Mt][1], 0, 0, 0);
        }
        #pragma unroll
        for (int Mt = 0; Mt < 4; ++Mt) {
            acc[Mt][0] = __builtin_amdgcn_mfma_f32_16x16x32_bf16(ah[Mt], cb[2], acc[Mt][0], 0, 0, 0);
            acc[Mt][1] = __builtin_amdgcn_mfma_f32_16x16x32_bf16(ah[Mt], cb[3], acc[Mt][1], 0, 0, 0);
        }
        #pragma unroll
        for (int Mt = 0; Mt < 4; ++Mt) {
            acc[Mt][0] = __builtin_amdgcn_mfma_f32_16x16x32_bf16(al[Mt], cb[0], acc[Mt][0], 0, 0, 0);
            acc[Mt][1] = __builtin_amdgcn_mfma_f32_16x16x32_bf16(al[Mt], cb[1], acc[Mt][1], 0, 0, 0);
        }
        cb[0] = nb[0]; cb[1] = nb[1]; cb[2] = nb[2]; cb[3] = nb[3];
    }
    // ---- z tap (B = Wx frags already in cb)
    {
        frag_ab ah[4], al[4];
        #pragma unroll
        for (int Mt = 0; Mt < 4; ++Mt) {
            const int r = Mt * 16 + rA;
            const int a = r * 64 + ((sA ^ (r & 3)) << 4);
            ah[Mt] = *reinterpret_cast<const frag_ab*>(&zbyh[a]);
            al[Mt] = *reinterpret_cast<const frag_ab*>(&zbyl[a]);
        }
        #pragma unroll
        for (int Mt = 0; Mt < 4; ++Mt) {
            acc[Mt][0] = __builtin_amdgcn_mfma_f32_16x16x32_bf16(ah[Mt], cb[0], acc[Mt][0], 0, 0, 0);
            acc[Mt][1] = __builtin_amdgcn_mfma_f32_16x16x32_bf16(ah[Mt], cb[1], acc[Mt][1], 0, 0, 0);
            acc[Mt][0] = __builtin_amdgcn_mfma_f32_16x16x32_bf16(ah[Mt], cb[2], acc[Mt][0], 0, 0, 0);
            acc[Mt][1] = __builtin_amdgcn_mfma_f32_16x16x32_bf16(ah[Mt], cb[3], acc[Mt][1], 0, 0, 0);
            acc[Mt][0] = __builtin_amdgcn_mfma_f32_16x16x32_bf16(al[Mt], cb[0], acc[Mt][0], 0, 0, 0);
            acc[Mt][1] = __builtin_amdgcn_mfma_f32_16x16x32_bf16(al[Mt], cb[1], acc[Mt][1], 0, 0, 0);
        }
    }

    // ---- scatter gates to LDS: col = gate*32 + chLocal
    #pragma unroll
    for (int Mt = 0; Mt < 4; ++Mt)
        #pragma unroll
        for (int gtI = 0; gtI < 2; ++gtI) {
            float* gp = &gbuf[(Mt * 16 + sA * 4) * GST + q * 32 + gtI * 16 + rA];
            gp[0]       = acc[Mt][gtI][0];
            gp[GST]     = acc[Mt][gtI][1];
            gp[2 * GST] = acc[Mt][gtI][2];
            gp[3 * GST] = acc[Mt][gtI][3];
        }
    __syncthreads();

    // ---- LSTM cell update: thread -> (fl = tid>>2, 8 local channels)
    const int fl = tid >> 2;              // 0..63
    const int c8 = (tid & 3) * 8;         // local channel block
    const int f = f0 + fl;
    const float* gr = &gbuf[fl * GST];
    const int chg = half * 32 + c8;       // global channel
    const int cix = (b * FF + f) * CC + chg;

    const float4 c01 = *reinterpret_cast<const float4*>(&c_in[cix]);
    const float4 c23 = *reinterpret_cast<const float4*>(&c_in[cix + 4]);
    const float cold[8] = {c01.x, c01.y, c01.z, c01.w, c23.x, c23.y, c23.z, c23.w};

    float hsum = 0.0f;
    float cv[8];
    short hh[8], hl[8];
    #pragma unroll
    for (int j = 0; j < 8; ++j) {
        const float gi = gr[c8 + j];
        const float gj = gr[32 + c8 + j];
        const float gf = gr[64 + c8 + j];
        const float go = gr[96 + c8 + j];
        const float cnew = cold[j] * sigmoidf_(gf + 1.0f) + sigmoidf_(gi) * tanhf_(gj);
        const float hnew = tanhf_(cnew) * sigmoidf_(go);
        cv[j] = cnew;
        split2(hnew, &hh[j], &hl[j]);
        hsum += hnew;
    }
    *reinterpret_cast<float4*>(&c_out[cix])     = make_float4(cv[0], cv[1], cv[2], cv[3]);
    *reinterpret_cast<float4*>(&c_out[cix + 4]) = make_float4(cv[4], cv[5], cv[6], cv[7]);
    const int hix = (b * HP + 4 + f) * CC + chg;
    *reinterpret_cast<frag_ab*>(&houth[hix]) = *reinterpret_cast<frag_ab*>(hh);
    *reinterpret_cast<frag_ab*>(&houtl[hix]) = *reinterpret_cast<frag_ab*>(hl);

    // 32-channel partial; cross-half combine via device atomics
    hsum += __shfl_xor(hsum, 1);
    hsum += __shfl_xor(hsum, 2);
    if ((tid & 3) == 0) {
        const int slot = b * FF + f;
        atomicAdd(&accW[slot], hsum);
        __threadfence();
        const int prev = atomicAdd(&cntW[slot], 1);
        if (prev == 1) {  // we are the second (last) half
            __threadfence();
            const float tot = atomicAdd(&accW[slot], 0.0f);  // coherent read
            out[(long)b * (TT * FF) + t * FF + f] = tanhf_(tot * (1.0f / 64.0f));
            atomicExch(&accW[slot], 0.0f);   // reset for next step / next replay
            atomicExch(&cntW[slot], 0);
        }
    }
}

extern "C" void kernel_launch(void* const* d_in, const int* in_sizes, int n_in,
                              void* d_out, int out_size, void* d_ws, size_t ws_size,
                              hipStream_t stream) {
    const float* z    = (const float*)d_in[0];
    const float* h0   = (const float*)d_in[1];
    const float* c0   = (const float*)d_in[2];
    const float* Wx   = (const float*)d_in[3];
    const float* Wh   = (const float*)d_in[4];
    const float* bias = (const float*)d_in[5];
    float* out = (float*)d_out;

    const int SEp = BB * HP * CC;   // 1,081,344 (padded h elems)
    const int SE  = BB * FF * CC;   // 1,048,576
    short* hAh = (short*)d_ws;
    short* hAl = hAh + SEp;
    short* hBh = hAl + SEp;
    short* hBl = hBh + SEp;
    float* cW  = (float*)(hBl + SEp);
    short* WhPh = (short*)(cW + SE);
    short* WhPl = WhPh + 9 * GG * CC;
    short* WxTh = WhPl + 9 * GG * CC;
    short* WxTl = WxTh + GG * 32;
    float* accW = (float*)(WxTl + GG * 32);
    int*   cntW = (int*)(accW + BB * FF);

    prep_kernel<<<(SEp + 255) / 256, 256, 0, stream>>>(Wh, Wx, h0, WhPh, WhPl,
                                                       WxTh, WxTl, hAh, hAl, hBh, hBl,
                                                       accW, cntW);

    dim3 grid(BB, FF / 64, 2);  // 64 x 4 x 2 = 512 blocks
    for (int t = 0; t < TT; ++t) {
        const short* hih = (t & 1) ? hBh : hAh;
        const short* hil = (t & 1) ? hBl : hAl;
        short* hoh = (t & 1) ? hAh : hBh;
        short* hol = (t & 1) ? hAl : hBl;
        const float* cin = (t == 0) ? c0 : cW;
        convlstm_step<<<grid, 256, 0, stream>>>(z, hih, hil, cin,
                                                WhPh, WhPl, WxTh, WxTl, bias,
                                                hoh, hol, cW, accW, cntW, out, t);
    }
}

// Round 7
// 1028.527 us; speedup vs baseline: 5.4529x; 5.4529x over previous
//
#include <hip/hip_runtime.h>
#include <hip/hip_bf16.h>

#define BB 64
#define TT 64
#define FF 256
#define CC 64
#define GG 256   // 4*C
#define HP 264   // padded f-rows per batch: 4 zero + 256 + 4 zero
#define GST 264  // gates LDS row stride (floats)

using frag_ab = __attribute__((ext_vector_type(8))) short;  // 8 bf16
using f32x4   = __attribute__((ext_vector_type(4))) float;

__device__ __forceinline__ float sigmoidf_(float x) {
    return 1.0f / (1.0f + __expf(-x));
}
__device__ __forceinline__ float tanhf_(float x) {
    const float e = __expf(2.0f * x);
    return 1.0f - 2.0f / (e + 1.0f);
}
__device__ __forceinline__ void split2(float v, short* hi, short* lo) {
    __hip_bfloat16 h = __float2bfloat16(v);
    __hip_bfloat16 l = __float2bfloat16(v - __bfloat162float(h));
    *hi = *reinterpret_cast<short*>(&h);
    *lo = *reinterpret_cast<short*>(&l);
}

// ---- prep: Wh -> packed [p=(k*2+kk)][g][cin32] hi/lo; Wx -> [g][32] hi/lo;
//      h0 -> padded (B,HP,C) hi/lo with zeroed halos in both ping-pong buffers
__global__ __launch_bounds__(256) void prep_kernel(
    const float* __restrict__ Wh, const float* __restrict__ Wx,
    const float* __restrict__ h0,
    short* __restrict__ WhPh, short* __restrict__ WhPl,
    short* __restrict__ WxTh, short* __restrict__ WxTl,
    short* __restrict__ hAh, short* __restrict__ hAl,
    short* __restrict__ hBh, short* __restrict__ hBl)
{
    const int n = blockIdx.x * 256 + threadIdx.x;
    if (n < BB * HP * CC) {
        const int c = n & 63;
        const int r = (n >> 6) % HP;
        const int b = n / (HP * CC);
        if (r < 4 || r >= 260) {
            hAh[n] = 0; hAl[n] = 0; hBh[n] = 0; hBl[n] = 0;
        } else {
            split2(h0[(b * FF + (r - 4)) * CC + c], &hAh[n], &hAl[n]);
        }
    }
    if (n < 9 * GG * CC) {
        const int c32 = n & 31;
        const int g = (n >> 5) & 255;
        const int p = n >> 13;
        const int k = p >> 1;
        const int cin = (p & 1) * 32 + c32;
        split2(Wh[(k * CC + cin) * GG + g], &WhPh[n], &WhPl[n]);
    }
    if (n < GG * 32) {
        const int kz = n & 31;
        const int g = n >> 5;
        split2(kz < 9 ? Wx[kz * GG + g] : 0.0f, &WxTh[n], &WxTl[n]);
    }
}

__global__ __launch_bounds__(512, 2) void convlstm_step(
    const float* __restrict__ z,
    const short* __restrict__ hinh, const short* __restrict__ hinl,  // padded (B,HP,C)
    const float* __restrict__ c_in,
    const short* __restrict__ WhPh, const short* __restrict__ WhPl,
    const short* __restrict__ WxTh, const short* __restrict__ WxTl,
    const float* __restrict__ bias,
    short* __restrict__ houth, short* __restrict__ houtl,            // padded
    float* __restrict__ c_out,
    float* __restrict__ out, int t)
{
    __shared__ __align__(16) char hbyh[72 * 128];   // h hi tile, swizzled
    __shared__ __align__(16) char hbyl[72 * 128];   // h lo tile
    __shared__ __align__(16) char zbyh[64 * 64];    // z hi tile [64 f][32 kz]
    __shared__ __align__(16) char zbyl[64 * 64];
    __shared__ __align__(16) float gbuf[32 * GST];  // gates fp32, two-pass (33.8 KB)

    const int b = blockIdx.x;
    const int f0 = blockIdx.y * 64;
    const int tid = threadIdx.x;
    const int lane = tid & 63;
    const int w = tid >> 6;          // 0..7 : owns g-cols [w*32, w*32+32)

    const int rA = lane & 15;
    const int sA = lane >> 4;
    const int gbase = w * 32;
    const int bln = rA * 32 + sA * 8;

    // ---- early global loads: phase-0 B frags + epilogue c_in + bias
    //      (latency hides under LDS staging + barrier)
    frag_ab cb[4];
    {
        const int o0 = gbase * 32 + bln;
        cb[0] = *reinterpret_cast<const frag_ab*>(WhPh + o0);
        cb[1] = *reinterpret_cast<const frag_ab*>(WhPh + o0 + 512);
        cb[2] = *reinterpret_cast<const frag_ab*>(WhPl + o0);
        cb[3] = *reinterpret_cast<const frag_ab*>(WhPl + o0 + 512);
    }
    const int flE = tid >> 4;             // epilogue row 0..31
    const int ch0E = (tid & 15) * 4;      // epilogue channel block
    const int cixE0 = (b * FF + f0 + flE) * CC + ch0E;
    const int cixE1 = cixE0 + 32 * CC;
    const float4 cold0 = *reinterpret_cast<const float4*>(&c_in[cixE0]);
    const float4 cold1 = *reinterpret_cast<const float4*>(&c_in[cixE1]);
    const float bv0 = bias[gbase + rA];
    const float bv1 = bias[gbase + 16 + rA];

    // ---- stage h tile rows f0..f0+71 (padded space; always in-bounds)
    for (int idx = tid; idx < 72 * 8; idx += 512) {
        const int row = idx >> 3, slot = idx & 7;
        const int off = (b * HP + f0 + row) * CC + slot * 8;
        const frag_ab vh = *reinterpret_cast<const frag_ab*>(hinh + off);
        const frag_ab vl = *reinterpret_cast<const frag_ab*>(hinl + off);
        const int a = row * 128 + ((slot ^ (row & 7)) << 4);
        *reinterpret_cast<frag_ab*>(&hbyh[a]) = vh;
        *reinterpret_cast<frag_ab*>(&hbyl[a]) = vl;
    }
    // ---- stage z tile [64 f][kz<9] hi+lo
    if (tid < 256) {
        const int row = tid >> 2, slot = tid & 3;
        const float* zr = z + ((long)b * TT + t) * FF;
        short vh[8], vl[8];
        #pragma unroll
        for (int j = 0; j < 8; ++j) {
            const int kz = slot * 8 + j;
            const int f = f0 + row - 4 + kz;
            const float val = (kz < 9 && f >= 0 && f < FF) ? zr[f] : 0.0f;
            split2(val, &vh[j], &vl[j]);
        }
        const int a = row * 64 + ((slot ^ (row & 3)) << 4);
        *reinterpret_cast<frag_ab*>(&zbyh[a]) = *reinterpret_cast<frag_ab*>(vh);
        *reinterpret_cast<frag_ab*>(&zbyl[a]) = *reinterpret_cast<frag_ab*>(vl);
    }
    __syncthreads();

    f32x4 acc[4][2];
    #pragma unroll
    for (int Mt = 0; Mt < 4; ++Mt) {
        acc[Mt][0] = (f32x4){bv0, bv0, bv0, bv0};
        acc[Mt][1] = (f32x4){bv1, bv1, bv1, bv1};
    }

    // ---- phase-0 A frags (k=0, kk=0)
    frag_ab cah[4], cal[4];
    #pragma unroll
    for (int Mt = 0; Mt < 4; ++Mt) {
        const int r = Mt * 16 + rA;
        const int a = r * 128 + ((sA ^ (r & 7)) << 4);
        cah[Mt] = *reinterpret_cast<const frag_ab*>(&hbyh[a]);
        cal[Mt] = *reinterpret_cast<const frag_ab*>(&hbyl[a]);
    }

    // ---- 19 uniform phases (18 Wh + 1 z-tap); A and B both prefetched 1 ahead
    #pragma unroll
    for (int p = 0; p < 19; ++p) {
        frag_ab nah[4], nal[4], nb[4];
        if (p < 17) {
            const int pn = p + 1;
            const int k = pn >> 1, kk = pn & 1;
            const int sl = kk * 4 + sA;
            #pragma unroll
            for (int Mt = 0; Mt < 4; ++Mt) {
                const int r = Mt * 16 + rA + k;
                const int a = r * 128 + ((sl ^ (r & 7)) << 4);
                nah[Mt] = *reinterpret_cast<const frag_ab*>(&hbyh[a]);
                nal[Mt] = *reinterpret_cast<const frag_ab*>(&hbyl[a]);
            }
            const int o0 = (pn * GG + gbase) * 32 + bln;
            nb[0] = *reinterpret_cast<const frag_ab*>(WhPh + o0);
            nb[1] = *reinterpret_cast<const frag_ab*>(WhPh + o0 + 512);
            nb[2] = *reinterpret_cast<const frag_ab*>(WhPl + o0);
            nb[3] = *reinterpret_cast<const frag_ab*>(WhPl + o0 + 512);
        } else if (p == 17) {
            // z-tap operands
            #pragma unroll
            for (int Mt = 0; Mt < 4; ++Mt) {
                const int r = Mt * 16 + rA;
                const int a = r * 64 + ((sA ^ (r & 3)) << 4);
                nah[Mt] = *reinterpret_cast<const frag_ab*>(&zbyh[a]);
                nal[Mt] = *reinterpret_cast<const frag_ab*>(&zbyl[a]);
            }
            const int o0 = gbase * 32 + bln;
            nb[0] = *reinterpret_cast<const frag_ab*>(WxTh + o0);
            nb[1] = *reinterpret_cast<const frag_ab*>(WxTh + o0 + 512);
            nb[2] = *reinterpret_cast<const frag_ab*>(WxTl + o0);
            nb[3] = *reinterpret_cast<const frag_ab*>(WxTl + o0 + 512);
        }
        __builtin_amdgcn_s_setprio(1);
        #pragma unroll
        for (int Mt = 0; Mt < 4; ++Mt) {
            acc[Mt][0] = __builtin_amdgcn_mfma_f32_16x16x32_bf16(cah[Mt], cb[0], acc[Mt][0], 0, 0, 0);
            acc[Mt][1] = __builtin_amdgcn_mfma_f32_16x16x32_bf16(cah[Mt], cb[1], acc[Mt][1], 0, 0, 0);
        }
        #pragma unroll
        for (int Mt = 0; Mt < 4; ++Mt) {
            acc[Mt][0] = __builtin_amdgcn_mfma_f32_16x16x32_bf16(cah[Mt], cb[2], acc[Mt][0], 0, 0, 0);
            acc[Mt][1] = __builtin_amdgcn_mfma_f32_16x16x32_bf16(cah[Mt], cb[3], acc[Mt][1], 0, 0, 0);
        }
        #pragma unroll
        for (int Mt = 0; Mt < 4; ++Mt) {
            acc[Mt][0] = __builtin_amdgcn_mfma_f32_16x16x32_bf16(cal[Mt], cb[0], acc[Mt][0], 0, 0, 0);
            acc[Mt][1] = __builtin_amdgcn_mfma_f32_16x16x32_bf16(cal[Mt], cb[1], acc[Mt][1], 0, 0, 0);
        }
        __builtin_amdgcn_s_setprio(0);
        if (p < 18) {
            #pragma unroll
            for (int Mt = 0; Mt < 4; ++Mt) { cah[Mt] = nah[Mt]; cal[Mt] = nal[Mt]; }
            cb[0] = nb[0]; cb[1] = nb[1]; cb[2] = nb[2]; cb[3] = nb[3];
        }
    }

    // ---- two-pass epilogue through 32-row gbuf
    #pragma unroll
    for (int pass = 0; pass < 2; ++pass) {
        if (pass) __syncthreads();   // pass-0 reads done before overwrite
        #pragma unroll
        for (int Mh = 0; Mh < 2; ++Mh) {
            const int Mt = pass * 2 + Mh;
            #pragma unroll
            for (int gtI = 0; gtI < 2; ++gtI) {
                const int g = gbase + gtI * 16 + rA;
                float* gp = &gbuf[(Mh * 16 + sA * 4) * GST + g];
                gp[0]       = acc[Mt][gtI][0];
                gp[GST]     = acc[Mt][gtI][1];
                gp[2 * GST] = acc[Mt][gtI][2];
                gp[3 * GST] = acc[Mt][gtI][3];
            }
        }
        __syncthreads();

        const int f = f0 + pass * 32 + flE;
        const float* gr = &gbuf[flE * GST];
        const f32x4 gi = *reinterpret_cast<const f32x4*>(gr + ch0E);
        const f32x4 gj = *reinterpret_cast<const f32x4*>(gr + 64 + ch0E);
        const f32x4 gf = *reinterpret_cast<const f32x4*>(gr + 128 + ch0E);
        const f32x4 go = *reinterpret_cast<const f32x4*>(gr + 192 + ch0E);

        const float4 cold = pass ? cold1 : cold0;
        const float co_[4] = {cold.x, cold.y, cold.z, cold.w};

        float hsum = 0.0f;
        float cv[4];
        short hh[4], hl[4];
        #pragma unroll
        for (int j = 0; j < 4; ++j) {
            const float cnew = co_[j] * sigmoidf_(gf[j] + 1.0f) + sigmoidf_(gi[j]) * tanhf_(gj[j]);
            const float hnew = tanhf_(cnew) * sigmoidf_(go[j]);
            cv[j] = cnew;
            split2(hnew, &hh[j], &hl[j]);
            hsum += hnew;
        }
        const int cix = (b * FF + f) * CC + ch0E;
        *reinterpret_cast<float4*>(&c_out[cix]) = make_float4(cv[0], cv[1], cv[2], cv[3]);
        const int hix = (b * HP + 4 + f) * CC + ch0E;
        *reinterpret_cast<uint2*>(&houth[hix]) = *reinterpret_cast<uint2*>(hh);
        *reinterpret_cast<uint2*>(&houtl[hix]) = *reinterpret_cast<uint2*>(hl);

        hsum += __shfl_xor(hsum, 1);
        hsum += __shfl_xor(hsum, 2);
        hsum += __shfl_xor(hsum, 4);
        hsum += __shfl_xor(hsum, 8);
        if ((tid & 15) == 0)
            out[(long)b * (TT * FF) + t * FF + f] = tanhf_(hsum * (1.0f / 64.0f));
    }
}

extern "C" void kernel_launch(void* const* d_in, const int* in_sizes, int n_in,
                              void* d_out, int out_size, void* d_ws, size_t ws_size,
                              hipStream_t stream) {
    const float* z    = (const float*)d_in[0];
    const float* h0   = (const float*)d_in[1];
    const float* c0   = (const float*)d_in[2];
    const float* Wx   = (const float*)d_in[3];
    const float* Wh   = (const float*)d_in[4];
    const float* bias = (const float*)d_in[5];
    float* out = (float*)d_out;

    const int SEp = BB * HP * CC;   // 1,081,344 (padded h elems)
    const int SE  = BB * FF * CC;   // 1,048,576
    short* hAh = (short*)d_ws;
    short* hAl = hAh + SEp;
    short* hBh = hAl + SEp;
    short* hBl = hBh + SEp;
    float* cW  = (float*)(hBl + SEp);
    short* WhPh = (short*)(cW + SE);
    short* WhPl = WhPh + 9 * GG * CC;
    short* WxTh = WhPl + 9 * GG * CC;
    short* WxTl = WxTh + GG * 32;

    prep_kernel<<<(SEp + 255) / 256, 256, 0, stream>>>(Wh, Wx, h0, WhPh, WhPl,
                                                       WxTh, WxTl, hAh, hAl, hBh, hBl);

    dim3 grid(BB, FF / 64);  // 64 x 4 = 256 blocks
    for (int t = 0; t < TT; ++t) {
        const short* hih = (t & 1) ? hBh : hAh;
        const short* hil = (t & 1) ? hBl : hAl;
        short* hoh = (t & 1) ? hAh : hBh;
        short* hol = (t & 1) ? hAl : hBl;
        const float* cin = (t == 0) ? c0 : cW;
        convlstm_step<<<grid, 512, 0, stream>>>(z, hih, hil, cin,
                                                WhPh, WhPl, WxTh, WxTl, bias,
                                                hoh, hol, cW, out, t);
    }
}